// Round 12
// baseline (161.201 us; speedup 1.0000x reference)
//
#include <hip/hip_runtime.h>

typedef __bf16 v8bf __attribute__((ext_vector_type(8)));
typedef float v4f __attribute__((ext_vector_type(4)));
typedef unsigned int v4u __attribute__((ext_vector_type(4)));
typedef unsigned int v2u __attribute__((ext_vector_type(2)));
typedef unsigned short u16;

#define DEVI static __device__ __forceinline__

DEVI float bf2f(u16 u) {
    union { float f; unsigned int i; } c; c.i = ((unsigned int)u) << 16; return c.f;
}
DEVI u16 f2bf(float f) {
    union { __bf16 b; u16 u; } c; c.b = (__bf16)f;   // native HW cvt, RNE
    return c.u;
}

union Frag { v4u u; v8bf v; u16 h[8]; };

#define GLD16(gptr, lptr) __builtin_amdgcn_global_load_lds( \
    (const __attribute__((address_space(1))) void*)(gptr),  \
    (__attribute__((address_space(3))) void*)(lptr), 16, 0, 0)

// ---------------------------------------------------------------------------
// fp32 -> bf16 convert (x, Wq, Wk, Wv packed, Wo) + gate precompute (seg 5):
// gates[token*4+g] = 3*sigmoid(x[token,0:12] . Wg[g])
// ---------------------------------------------------------------------------
__global__ __launch_bounds__(256) void convert6(
    const float* __restrict__ x, const float* __restrict__ wq,
    const float* __restrict__ wk, const float* __restrict__ wv,
    const float* __restrict__ wo, const float* __restrict__ Wg,
    u16* __restrict__ xb, u16* __restrict__ wb, u16* __restrict__ wob,
    float* __restrict__ gates)
{
    if (blockIdx.y == 5) {
        const int stride = gridDim.x * 256;
        for (int i = blockIdx.x * 256 + threadIdx.x; i < 4096 * 4; i += stride) {
            const int token = i >> 2, g = i & 3;
            float dot = 0.f;
#pragma unroll
            for (int c = 0; c < 12; c++)
                dot += x[token * 1024 + c] * Wg[g * 12 + c];
            gates[i] = 3.f / (1.f + __expf(-dot));
        }
        return;
    }
    const float* src; u16* dst; int n;
    switch (blockIdx.y) {
        case 0: src = x;  dst = xb;               n = 4096 * 1024; break;
        case 1: src = wq; dst = wb;               n = 1024 * 1024; break;
        case 2: src = wk; dst = wb + 1024 * 1024; n = 256 * 1024;  break;
        case 3: src = wv; dst = wb + 1280 * 1024; n = 256 * 1024;  break;
        default: src = wo; dst = wob;             n = 1024 * 1024; break;
    }
    const int stride = gridDim.x * 256 * 4;
    for (int i = (blockIdx.x * 256 + threadIdx.x) * 4; i < n; i += stride) {
        const float4 f = *(const float4*)(src + i);
        v2u p;
        p[0] = (unsigned int)f2bf(f.x) | ((unsigned int)f2bf(f.y) << 16);
        p[1] = (unsigned int)f2bf(f.z) | ((unsigned int)f2bf(f.w) << 16);
        *(v2u*)(dst + i) = p;
    }
}

// ---------------------------------------------------------------------------
// GEMM: C = A[M,K](bf16) * B[N,K]^T(bf16), M=4096, K=1024, tile 64x128 BK=64.
// Grid (m,n) -> bid = n*64+m, 64%8==0: n-tiles of an m-row share an XCD.
// QKV=true fused epilogues:
//   Q/K heads: in-register RoPE + RMS-norm(*1.2) -> qn/kn bf16
//   V heads (blockIdx.y 10,11 — block-uniform): gate+ve, then transpose
//     through the (dead) staging LDS straight into vt — vn/vtrans eliminated.
// QKV=false: plain fp32 store (output projection).
// ---------------------------------------------------------------------------
template <bool QKV>
__global__ __launch_bounds__(256) void gemm_bt(
    const u16* __restrict__ A, const u16* __restrict__ B,
    void* __restrict__ Cv, int N,
    const float* __restrict__ cs, const float* __restrict__ sn,
    const float* __restrict__ gates, const float* __restrict__ ve,
    u16* __restrict__ qn, u16* __restrict__ kn, u16* __restrict__ vt)
{
    __shared__ __align__(16) u16 smem[12288];   // As[4096] + Bs[8192]
    u16* As = smem;
    u16* Bs = smem + 4096;
    const int tid  = threadIdx.x;
    const int lane = tid & 63, l15 = lane & 15, quad = (lane >> 4) & 3;
    const int w    = tid >> 6;
    const int wr   = (w >> 1) * 32, wc = (w & 1) * 64;
    const int m0   = blockIdx.x * 64, n0 = blockIdx.y * 128;

    const u16* ab = A + m0 * 1024;
    const u16* bb = B + n0 * 1024;
    const int r0 = tid >> 3;
    const int c0 = (tid & 7) * 8;
    const u16* ag = ab + r0 * 1024 + c0;
    const u16* bg = bb + r0 * 1024 + c0;
    u16* al = &As[r0 * 64 + c0];
    u16* bl = &Bs[r0 * 64 + c0];

    v4f acc[2][4];
    const v4f vzero = {0.f, 0.f, 0.f, 0.f};
#pragma unroll
    for (int i = 0; i < 2; i++)
#pragma unroll
        for (int j = 0; j < 4; j++) acc[i][j] = vzero;

    for (int k0 = 0; k0 < 1024; k0 += 64) {
        __syncthreads();
        GLD16(ag + k0,             al);
        GLD16(ag + k0 + 32 * 1024, al + 32 * 64);
        GLD16(bg + k0,             bl);
        GLD16(bg + k0 + 32 * 1024, bl + 32 * 64);
        GLD16(bg + k0 + 64 * 1024, bl + 64 * 64);
        GLD16(bg + k0 + 96 * 1024, bl + 96 * 64);
        __syncthreads();
#pragma unroll
        for (int ks = 0; ks < 2; ks++) {
            v8bf af[2];
#pragma unroll
            for (int mi = 0; mi < 2; mi++)
                af[mi] = *(const v8bf*)&As[(wr + mi * 16 + l15) * 64 + ks * 32 + quad * 8];
#pragma unroll
            for (int ni = 0; ni < 4; ni++) {
                v8bf bv = *(const v8bf*)&Bs[(wc + ni * 16 + l15) * 64 + ks * 32 + quad * 8];
#pragma unroll
                for (int mi = 0; mi < 2; mi++)
                    acc[mi][ni] = __builtin_amdgcn_mfma_f32_16x16x32_bf16(af[mi], bv, acc[mi][ni], 0, 0, 0);
            }
        }
    }

    if (!QKV) {
#pragma unroll
        for (int mi = 0; mi < 2; mi++) {
            const int row = m0 + wr + mi * 16 + quad * 4;
#pragma unroll
            for (int ni = 0; ni < 4; ni++) {
                const int col = n0 + wc + ni * 16 + l15;
#pragma unroll
                for (int r = 0; r < 4; r++)
                    ((float*)Cv)[(row + r) * N + col] = acc[mi][ni][r];
            }
        }
        return;
    }

    const int hcol = n0 + wc;          // start col of this wave's head
    if (hcol < 1280) {                 // Q or K head: RoPE + RMS-norm
        const bool isQ = (hcol < 1024);
        u16* dst = isQ ? (qn + (hcol >> 6) * 64) : (kn + ((hcol - 1024) >> 6) * 64);
        const int dstride = isQ ? 1024 : 256;
#pragma unroll
        for (int mi = 0; mi < 2; mi++) {
#pragma unroll
            for (int r = 0; r < 4; r++) {
                const int row = m0 + wr + mi * 16 + quad * 4 + r;
                const int pos = row & 1023;
                const float c0_ = cs[pos * 32 + l15],      s0_ = sn[pos * 32 + l15];
                const float c1_ = cs[pos * 32 + 16 + l15], s1_ = sn[pos * 32 + 16 + l15];
                const float y0 = acc[mi][0][r] * c0_ + acc[mi][2][r] * s0_;
                const float y2 = acc[mi][2][r] * c0_ - acc[mi][0][r] * s0_;
                const float y1 = acc[mi][1][r] * c1_ + acc[mi][3][r] * s1_;
                const float y3 = acc[mi][3][r] * c1_ - acc[mi][1][r] * s1_;
                float ss = y0 * y0 + y1 * y1 + y2 * y2 + y3 * y3;
#pragma unroll
                for (int off = 8; off >= 1; off >>= 1)
                    ss += __shfl_xor(ss, off, 64);
                const float inv = rsqrtf(ss * (1.0f / 64.0f) + 1.1920929e-7f) * 1.2f;
                u16* d = dst + row * dstride;
                d[l15]      = f2bf(y0 * inv);
                d[16 + l15] = f2bf(y1 * inv);
                d[32 + l15] = f2bf(y2 * inv);
                d[48 + l15] = f2bf(y3 * inv);
            }
        }
    } else {
        // V heads (block-uniform: all 4 waves here). gate+ve, then transpose
        // through the now-dead staging LDS into vt[((b*4+g)*64+d)*1024 + t].
        const int g  = (hcol - 1280) >> 6;
        const int hb = wc >> 6;                       // head slot in block
        u16* vbuf = smem;                             // [2][64][72] u16 = 18 KB
        __syncthreads();                              // staging LDS now dead
#pragma unroll
        for (int mi = 0; mi < 2; mi++) {
#pragma unroll
            for (int r = 0; r < 4; r++) {
                const int tl  = wr + mi * 16 + quad * 4 + r;   // local token
                const int row = m0 + tl;
                const float gate = gates[row * 4 + g];
                const float* vesrc = ve + row * 256 + g * 64;
#pragma unroll
                for (int ni = 0; ni < 4; ni++)
                    vbuf[hb * 4608 + tl * 72 + ni * 16 + l15] =
                        f2bf(acc[mi][ni][r] + gate * vesrc[ni * 16 + l15]);
            }
        }
        __syncthreads();
        {
            const int rowi = tid >> 1;                // 0..127: (hb2, d)
            const int hb2 = rowi >> 6, d = rowi & 63;
            const int gg = ((n0 - 1280) >> 6) + hb2;
            const int bB = m0 >> 10, t0 = m0 & 1023;
            const int half = (tid & 1) * 32;
            Frag f[4];
#pragma unroll
            for (int ck = 0; ck < 4; ck++)
#pragma unroll
                for (int j = 0; j < 8; j++)
                    f[ck].h[j] = vbuf[hb2 * 4608 + (half + ck * 8 + j) * 72 + d];
            u16* dst = vt + ((bB * 4 + gg) * 64 + d) * 1024 + t0 + half;
#pragma unroll
            for (int ck = 0; ck < 4; ck++)
                *(v4u*)(dst + ck * 8) = f[ck].u;
        }
    }
}

// ---------------------------------------------------------------------------
// Sliding-window flash attention v7: fixed-max base-2 softmax (Q pre-scaled
// by 0.125*log2e; p = exp2(a - 12*log2e)). K-fragments loaded once per ni
// (mi-inner) — 8 ds_read_b128/tile instead of 16. Wave owns 32 q-rows;
// block = 128 q-rows. Grid (qb=8, h=16, b=4) = 512.
// ---------------------------------------------------------------------------
__global__ __launch_bounds__(256) void attn(
    const u16* __restrict__ qn, const u16* __restrict__ kn,
    const u16* __restrict__ vt, u16* __restrict__ yo)
{
    __shared__ __align__(16) u16 Ks[64 * 72];
    __shared__ __align__(16) u16 VTs[64 * 72];
    __shared__ __align__(16) u16 Ps[4][32 * 72];
    const int tid  = threadIdx.x;
    const int w    = tid >> 6, lane = tid & 63, l15 = lane & 15, quad = (lane >> 4) & 3;
    const int qb   = blockIdx.x, h = blockIdx.y, b = blockIdx.z;
    const int g    = h >> 2;
    const int qbase = qb * 128;
    const int qabs0 = qbase + w * 32;
    const int tok0  = b * 1024 + qabs0;
    u16* pw = Ps[w];

    v8bf qf[2][2];
#pragma unroll
    for (int mi = 0; mi < 2; mi++)
#pragma unroll
        for (int ks = 0; ks < 2; ks++) {
            Frag f;
            f.u = *(const v4u*)&qn[(tok0 + mi * 16 + l15) * 1024 + h * 64 + ks * 32 + quad * 8];
#pragma unroll
            for (int j = 0; j < 8; j++) f.h[j] = f2bf(0.18033688f * bf2f(f.h[j]));  // 0.125*log2e
            qf[mi][ks] = f.v;
        }

    v4f o[2][4];
    float li[2][4];
    const v4f vzero = {0.f, 0.f, 0.f, 0.f};
#pragma unroll
    for (int mi = 0; mi < 2; mi++) {
#pragma unroll
        for (int nd = 0; nd < 4; nd++) o[mi][nd] = vzero;
#pragma unroll
        for (int r = 0; r < 4; r++) li[mi][r] = 0.f;
    }

    const int kstart = (qbase >= 256) ? qbase - 256 : 0;
    const int kend   = qbase + 64;
    for (int kbase = kstart; kbase <= kend; kbase += 64) {
        __syncthreads();
        {
            const int row = tid >> 2, ch = (tid & 3) * 16;
            const int goff = (b * 1024 + kbase + row) * 256 + g * 64 + ch;
            *(v4u*)&Ks[row * 72 + ch]     = *(const v4u*)&kn[goff];
            *(v4u*)&Ks[row * 72 + ch + 8] = *(const v4u*)&kn[goff + 8];
            const u16* vsrc = vt + ((b * 4 + g) * 64 + row) * 1024 + kbase + ch;
            *(v4u*)&VTs[row * 72 + ch]     = *(const v4u*)vsrc;
            *(v4u*)&VTs[row * 72 + ch + 8] = *(const v4u*)(vsrc + 8);
        }
        __syncthreads();

        bool skip2[2][4], full2[2][4];
#pragma unroll
        for (int mi = 0; mi < 2; mi++)
#pragma unroll
            for (int ni = 0; ni < 4; ni++) {
                const int qw = qabs0 + mi * 16;
                const int left = kbase + ni * 16;
                skip2[mi][ni] = (left > qw + 15) || (qw - (left + 15) > 256);
                full2[mi][ni] = ((left + 15) <= qw) && ((qw + 15 - left) <= 256);
            }

#pragma unroll
        for (int ni = 0; ni < 4; ni++) {
            if (skip2[0][ni] && skip2[1][ni]) {
#pragma unroll
                for (int mi = 0; mi < 2; mi++)
#pragma unroll
                    for (int r = 0; r < 4; r++)
                        pw[(mi * 16 + quad * 4 + r) * 72 + ni * 16 + l15] = 0;
                continue;
            }
            v8bf kf0 = *(const v8bf*)&Ks[(ni * 16 + l15) * 72 + quad * 8];
            v8bf kf1 = *(const v8bf*)&Ks[(ni * 16 + l15) * 72 + 32 + quad * 8];
#pragma unroll
            for (int mi = 0; mi < 2; mi++) {
                if (skip2[mi][ni]) {
#pragma unroll
                    for (int r = 0; r < 4; r++)
                        pw[(mi * 16 + quad * 4 + r) * 72 + ni * 16 + l15] = 0;
                    continue;
                }
                v4f a = vzero;
                a = __builtin_amdgcn_mfma_f32_16x16x32_bf16(qf[mi][0], kf0, a, 0, 0, 0);
                a = __builtin_amdgcn_mfma_f32_16x16x32_bf16(qf[mi][1], kf1, a, 0, 0, 0);
                if (!full2[mi][ni]) {
                    const int kj = kbase + ni * 16 + l15;
#pragma unroll
                    for (int r = 0; r < 4; r++) {
                        const int qi = qabs0 + mi * 16 + quad * 4 + r;
                        if (!((kj <= qi) && (qi - kj <= 256))) a[r] = -1e30f;
                    }
                }
#pragma unroll
                for (int r = 0; r < 4; r++) {
                    const float p = exp2f(a[r] - 17.312340f);   // 12*log2e
                    li[mi][r] += p;
                    pw[(mi * 16 + quad * 4 + r) * 72 + ni * 16 + l15] = f2bf(p);
                }
            }
        }

#pragma unroll
        for (int mi = 0; mi < 2; mi++)
#pragma unroll
            for (int ks = 0; ks < 2; ks++) {
                if (skip2[mi][2 * ks] && skip2[mi][2 * ks + 1]) continue;
                v8bf af = *(const v8bf*)&pw[(mi * 16 + l15) * 72 + ks * 32 + quad * 8];
#pragma unroll
                for (int nd = 0; nd < 4; nd++) {
                    v8bf bv = *(const v8bf*)&VTs[(nd * 16 + l15) * 72 + ks * 32 + quad * 8];
                    o[mi][nd] = __builtin_amdgcn_mfma_f32_16x16x32_bf16(af, bv, o[mi][nd], 0, 0, 0);
                }
            }
    }

#pragma unroll
    for (int mi = 0; mi < 2; mi++) {
#pragma unroll
        for (int off = 8; off >= 1; off >>= 1)
#pragma unroll
            for (int r = 0; r < 4; r++)
                li[mi][r] += __shfl_xor(li[mi][r], off, 64);
        float inv[4];
#pragma unroll
        for (int r = 0; r < 4; r++) inv[r] = 1.f / li[mi][r];
#pragma unroll
        for (int nd = 0; nd < 4; nd++) {
            const int col = h * 64 + nd * 16 + l15;
#pragma unroll
            for (int r = 0; r < 4; r++) {
                const int row = tok0 + mi * 16 + quad * 4 + r;
                yo[row * 1024 + col] = f2bf(o[mi][nd][r] * inv[r]);
            }
        }
    }
}

// ---------------------------------------------------------------------------
extern "C" void kernel_launch(void* const* d_in, const int* in_sizes, int n_in,
                              void* d_out, int out_size, void* d_ws, size_t ws_size,
                              hipStream_t stream)
{
    const float* x  = (const float*)d_in[0];
    const float* ve = (const float*)d_in[1];
    const float* cs = (const float*)d_in[2];
    const float* sn = (const float*)d_in[3];
    const float* Wq = (const float*)d_in[4];
    const float* Wk = (const float*)d_in[5];
    const float* Wv = (const float*)d_in[6];
    const float* Wo = (const float*)d_in[7];
    const float* Wg = (const float*)d_in[8];
    // d_in[9] = window_size (fixed 256, hard-coded)

    u16*   xb    = (u16*)d_ws;                 // 4096 x 1024
    u16*   wb    = xb  + 4096 * 1024;          // 1536 x 1024  [Wq;Wk;Wv]
    u16*   wob   = wb  + 1536 * 1024;          // 1024 x 1024  Wo
    u16*   qn    = wob + 1024 * 1024;          // 4096 x 1024
    u16*   kn    = qn  + 4096 * 1024;          // 4096 x 256
    u16*   vt    = kn  + 4096 * 256;           // [4][4][64][1024]
    u16*   ay    = vt  + 4096 * 256;           // 4096 x 1024 attention out
    float* gates = (float*)(ay + 4096 * 1024); // 4096 x 4

    convert6<<<dim3(512, 6), 256, 0, stream>>>(x, Wq, Wk, Wv, Wo, Wg, xb, wb, wob, gates);
    gemm_bt<true><<<dim3(64, 12), 256, 0, stream>>>(xb, wb, nullptr, 1536,
                                                    cs, sn, gates, ve, qn, kn, vt);
    attn<<<dim3(8, 16, 4), 256, 0, stream>>>(qn, kn, vt, ay);
    gemm_bt<false><<<dim3(64, 8), 256, 0, stream>>>(ay, wob, d_out, 1024,
                                                    nullptr, nullptr, nullptr, nullptr,
                                                    nullptr, nullptr, nullptr);
}